// Round 1
// 6661.341 us; speedup vs baseline: 1.8601x; 1.8601x over previous
//
#include <hip/hip_runtime.h>
#include <math.h>

// Problem constants
#define B_  128
#define V_  30000
#define T_  50
#define K_  50
#define HE_ 256
#define TH_ 800
#define E_  300
#define L_  3

#define LOGD_ (-5.2983173665480363f)   // log(0.005) in f32

// ---------------------------------------------------------------------------
// Generic f32 NT GEMM: C[M,N] = A[M,K] * B[N,K]^T  (A,B row-major, K contiguous)
// mode: 0 = plain store, 1 = tanh(x + bias[col]), 2 = x + bias[col]
//       3 = split-K atomic accumulate (C must be pre-zeroed; bias ignored)
// gridDim.z = number of K chunks; kchunk = K elements per chunk (multiple of
// TK for all split launches in this file; exact tail only hit when z==1).
// ---------------------------------------------------------------------------
#define TM 64
#define TN 64
#define TK 16

__global__ __launch_bounds__(256) void gemm_nt(
    const float* __restrict__ A, int lda, int M,
    const float* __restrict__ B, int ldb, int N,
    int K,
    float* __restrict__ C, int ldc,
    const float* __restrict__ bias, int mode, int kchunk)
{
    __shared__ float As[TK][TM + 4];
    __shared__ float Bs[TK][TN + 4];
    const int tid = threadIdx.x;
    const int bm = blockIdx.y * TM;
    const int bn = blockIdx.x * TN;
    const int tx = tid & 15;       // 0..15 col group
    const int ty = tid >> 4;       // 0..15 row group
    const int lr = tid >> 2;       // 0..63 tile row for loads
    const int lc = (tid & 3) << 2; // 0,4,8,12 k offset for loads

    float acc[4][4];
#pragma unroll
    for (int i = 0; i < 4; ++i)
#pragma unroll
        for (int j = 0; j < 4; ++j) acc[i][j] = 0.f;

    const int kbeg = blockIdx.z * kchunk;
    const int kend = min(K, kbeg + kchunk);

    for (int k0 = kbeg; k0 < kend; k0 += TK) {
        // stage A tile
        {
            float v0 = 0.f, v1 = 0.f, v2 = 0.f, v3 = 0.f;
            int gr = bm + lr;
            if (gr < M) {
                const float* p = A + (size_t)gr * lda + k0 + lc;
                int rem = K - (k0 + lc);
                if (rem >= 4) {
                    float2 a0 = *(const float2*)p;
                    float2 a1 = *(const float2*)(p + 2);
                    v0 = a0.x; v1 = a0.y; v2 = a1.x; v3 = a1.y;
                } else {
                    if (rem > 0) v0 = p[0];
                    if (rem > 1) v1 = p[1];
                    if (rem > 2) v2 = p[2];
                }
            }
            As[lc + 0][lr] = v0; As[lc + 1][lr] = v1;
            As[lc + 2][lr] = v2; As[lc + 3][lr] = v3;
        }
        // stage B tile
        {
            float v0 = 0.f, v1 = 0.f, v2 = 0.f, v3 = 0.f;
            int gr = bn + lr;
            if (gr < N) {
                const float* p = B + (size_t)gr * ldb + k0 + lc;
                int rem = K - (k0 + lc);
                if (rem >= 4) {
                    float2 a0 = *(const float2*)p;
                    float2 a1 = *(const float2*)(p + 2);
                    v0 = a0.x; v1 = a0.y; v2 = a1.x; v3 = a1.y;
                } else {
                    if (rem > 0) v0 = p[0];
                    if (rem > 1) v1 = p[1];
                    if (rem > 2) v2 = p[2];
                }
            }
            Bs[lc + 0][lr] = v0; Bs[lc + 1][lr] = v1;
            Bs[lc + 2][lr] = v2; Bs[lc + 3][lr] = v3;
        }
        __syncthreads();
#pragma unroll
        for (int kk = 0; kk < TK; ++kk) {
            float a[4], b[4];
#pragma unroll
            for (int i = 0; i < 4; ++i) a[i] = As[kk][ty * 4 + i];
#pragma unroll
            for (int j = 0; j < 4; ++j) b[j] = Bs[kk][tx * 4 + j];
#pragma unroll
            for (int i = 0; i < 4; ++i)
#pragma unroll
                for (int j = 0; j < 4; ++j) acc[i][j] += a[i] * b[j];
        }
        __syncthreads();
    }

#pragma unroll
    for (int i = 0; i < 4; ++i) {
        int row = bm + ty * 4 + i;
        if (row >= M) continue;
#pragma unroll
        for (int j = 0; j < 4; ++j) {
            int col = bn + tx * 4 + j;
            if (col >= N) continue;
            float v = acc[i][j];
            if (mode == 3) {
                atomicAdd(&C[(size_t)row * ldc + col], v);
            } else {
                if (mode == 1) v = tanhf(v + bias[col]);
                else if (mode == 2) v = v + bias[col];
                C[(size_t)row * ldc + col] = v;
            }
        }
    }
}

// ---------------------------------------------------------------------------
// Epilogue for split-K GEMMs: C[i] = (tanh)(C[i] + bias[col]).
// mode 1 = tanh(x+b), 2 = x+b
// ---------------------------------------------------------------------------
__global__ __launch_bounds__(256) void bias_act(
    float* __restrict__ C, const float* __restrict__ bias,
    int total, int N, int mode)
{
    int idx = blockIdx.x * 256 + threadIdx.x;
    if (idx >= total) return;
    int j = idx % N;
    float v = C[idx] + bias[j];
    if (mode == 1) v = tanhf(v);
    C[idx] = v;
}

// ---------------------------------------------------------------------------
// Row sums of X -> 1/sum
// ---------------------------------------------------------------------------
__global__ __launch_bounds__(256) void rowsum_inv(const float* __restrict__ X,
                                                  float* __restrict__ inv)
{
    int b = blockIdx.x;
    const float4* p = (const float4*)(X + (size_t)b * V_);
    float s = 0.f;
    for (int i = threadIdx.x; i < V_ / 4; i += 256) {
        float4 v = p[i];
        s += v.x + v.y + v.z + v.w;
    }
    for (int off = 32; off; off >>= 1) s += __shfl_down(s, off);
    __shared__ float red[4];
    int wid = threadIdx.x >> 6, lane = threadIdx.x & 63;
    if (lane == 0) red[wid] = s;
    __syncthreads();
    if (threadIdx.x == 0) inv[b] = 1.f / (red[0] + red[1] + red[2] + red[3]);
}

// ---------------------------------------------------------------------------
// Single-block LSTM layer scan. Input projections (Wi@x_t) precomputed.
// 1024 threads; thread j computes gate row j each step.
// ---------------------------------------------------------------------------
__global__ __launch_bounds__(1024) void lstm_scan(
    const float* __restrict__ Xproj,  // [T,1024]
    const float* __restrict__ Whh,    // [1024,256]
    const float* __restrict__ bih,    // [1024]
    const float* __restrict__ bhh,    // [1024]
    float* __restrict__ Hout)         // [T,256]
{
    __shared__ float h[HE_];
    __shared__ float g[4 * HE_];
    const int j = threadIdx.x;
    float c = 0.f;
    if (j < HE_) h[j] = 0.f;
    const float bias = bih[j] + bhh[j];
    const float4* wr = (const float4*)(Whh + (size_t)j * HE_);
    __syncthreads();
    for (int t = 0; t < T_; ++t) {
        float acc = 0.f;
#pragma unroll 8
        for (int i = 0; i < HE_ / 4; ++i) {
            float4 w = wr[i];
            float4 hv = *(const float4*)(&h[i * 4]);
            acc += w.x * hv.x + w.y * hv.y + w.z * hv.z + w.w * hv.w;
        }
        g[j] = acc + Xproj[t * 4 * HE_ + j] + bias;
        __syncthreads();
        if (j < HE_) {
            float gi = g[j];
            float gf = g[HE_ + j];
            float gg = g[2 * HE_ + j];
            float go = g[3 * HE_ + j];
            float si = 1.f / (1.f + expf(-gi));
            float sf = 1.f / (1.f + expf(-gf));
            float so = 1.f / (1.f + expf(-go));
            c = sf * c + si * tanhf(gg);
            float hn = so * tanhf(c);
            h[j] = hn;
            Hout[t * HE_ + j] = hn;
        }
        __syncthreads();
    }
}

// ---------------------------------------------------------------------------
// Sequential eta recurrence (tiny). One wave. Also emits kl_eta.
// ---------------------------------------------------------------------------
__global__ __launch_bounds__(64) void eta_scan(
    const float* __restrict__ rnn_out,  // [T,HE]
    const float* __restrict__ Wmu, const float* __restrict__ bmu,
    const float* __restrict__ Wls, const float* __restrict__ bls,
    float* __restrict__ etas,           // [T,K]
    float* __restrict__ kl_eta_out)
{
    __shared__ float hbuf[HE_ + K_];
    const int lane = threadIdx.x;
    if (lane < K_) hbuf[HE_ + lane] = 0.f;
    float kl = 0.f;
    __syncthreads();
    for (int t = 0; t < T_; ++t) {
        for (int i = lane; i < HE_; i += 64) hbuf[i] = rnn_out[t * HE_ + i];
        __syncthreads();
        float mu = 0.f;
        if (lane < K_) {
            const float* wm = Wmu + lane * (HE_ + K_);
            const float* wl = Wls + lane * (HE_ + K_);
            float am = 0.f, al = 0.f;
            for (int i = 0; i < HE_ + K_; ++i) {
                float hv = hbuf[i];
                am += wm[i] * hv;
                al += wl[i] * hv;
            }
            mu = am + bmu[lane];
            float ls = al + bls[lane];
            float eprev = hbuf[HE_ + lane];
            float pls = (t == 0) ? 0.f : LOGD_;
            float d = mu - eprev;
            kl += 0.5f * ((expf(ls) + d * d) / (expf(pls) + 1e-6f) - 1.f + pls - ls);
            etas[t * K_ + lane] = mu;
        }
        __syncthreads();
        if (lane < K_) hbuf[HE_ + lane] = mu;
        __syncthreads();
    }
    for (int off = 32; off; off >>= 1) kl += __shfl_down(kl, off);
    if (lane == 0) *kl_eta_out = kl;
}

// ---------------------------------------------------------------------------
// h1 = tanh(inv[b]*C1 + etas[ts[b]]·W1[:,V:] + b1)   (in place on C1)
// ---------------------------------------------------------------------------
__global__ __launch_bounds__(256) void h1_epilogue(
    const float* __restrict__ C1, const float* __restrict__ inv,
    const float* __restrict__ etas, const int* __restrict__ ts,
    const float* __restrict__ W1, const float* __restrict__ b1,
    float* __restrict__ h1)
{
    int idx = blockIdx.x * 256 + threadIdx.x;
    if (idx >= B_ * TH_) return;
    int b = idx / TH_, j = idx % TH_;
    const float* e = etas + ts[b] * K_;
    const float* w = W1 + (size_t)j * (V_ + K_) + V_;
    float s = 0.f;
#pragma unroll
    for (int k = 0; k < K_; ++k) s += e[k] * w[k];
    h1[idx] = tanhf(C1[idx] * inv[b] + s + b1[j]);
}

// ---------------------------------------------------------------------------
// theta = softmax(mu_t) rows; kl_theta accumulated. One block (1 wave) per b.
// ---------------------------------------------------------------------------
__global__ __launch_bounds__(64) void theta_kernel(
    const float* __restrict__ mu_t, const float* __restrict__ ls_t,
    const float* __restrict__ etas, const int* __restrict__ ts,
    float* __restrict__ theta, float* __restrict__ kl_out)
{
    int b = blockIdx.x;
    int lane = threadIdx.x;
    bool ok = lane < K_;
    float m = ok ? mu_t[b * K_ + lane] : -3.4e38f;
    float mx = m;
    for (int off = 32; off; off >>= 1) mx = fmaxf(mx, __shfl_down(mx, off));
    mx = __shfl(mx, 0);
    float e = ok ? expf(m - mx) : 0.f;
    float s = e;
    for (int off = 32; off; off >>= 1) s += __shfl_down(s, off);
    s = __shfl(s, 0);
    if (ok) theta[b * K_ + lane] = e / s;
    float kl = 0.f;
    if (ok) {
        float ls = ls_t[b * K_ + lane];
        float d = m - etas[ts[b] * K_ + lane];
        kl = 0.5f * ((expf(ls) + d * d) / (1.f + 1e-6f) - 1.f - ls);
    }
    for (int off = 32; off; off >>= 1) kl += __shfl_down(kl, off);
    if (lane == 0) atomicAdd(kl_out, kl);
}

// ---------------------------------------------------------------------------
// alphas[t*K+k, e] = mu_q_alpha[k, t, e]
// ---------------------------------------------------------------------------
__global__ __launch_bounds__(256) void transpose_alphas(
    const float* __restrict__ mu, float* __restrict__ out)
{
    int idx = blockIdx.x * 256 + threadIdx.x;
    if (idx >= T_ * K_ * E_) return;
    int t = idx / (K_ * E_);
    int r = idx % (K_ * E_);
    int k = r / E_;
    int e = r % E_;
    out[idx] = mu[((size_t)k * T_ + t) * E_ + e];
}

// ---------------------------------------------------------------------------
// In-place row softmax (rows of length V), online max/sum pass + write pass.
// ---------------------------------------------------------------------------
__global__ __launch_bounds__(256) void softmax_rows(float* __restrict__ logits)
{
    int row = blockIdx.x;
    float4* p4 = (float4*)(logits + (size_t)row * V_);
    float m = -3.4e38f, s = 0.f;
    for (int i = threadIdx.x; i < V_ / 4; i += 256) {
        float4 v = p4[i];
        float vm = fmaxf(fmaxf(v.x, v.y), fmaxf(v.z, v.w));
        if (vm > m) { s *= expf(m - vm); m = vm; }
        s += expf(v.x - m) + expf(v.y - m) + expf(v.z - m) + expf(v.w - m);
    }
    // wave combine (m,s)
    for (int off = 32; off; off >>= 1) {
        float om = __shfl_down(m, off);
        float os = __shfl_down(s, off);
        float nm = fmaxf(m, om);
        s = s * expf(m - nm) + os * expf(om - nm);
        m = nm;
    }
    __shared__ float redm[4], reds[4];
    __shared__ float fm, fs;
    int wid = threadIdx.x >> 6, lane = threadIdx.x & 63;
    if (lane == 0) { redm[wid] = m; reds[wid] = s; }
    __syncthreads();
    if (threadIdx.x == 0) {
        float M = fmaxf(fmaxf(redm[0], redm[1]), fmaxf(redm[2], redm[3]));
        float S = reds[0] * expf(redm[0] - M) + reds[1] * expf(redm[1] - M) +
                  reds[2] * expf(redm[2] - M) + reds[3] * expf(redm[3] - M);
        fm = M; fs = 1.f / S;
    }
    __syncthreads();
    float M = fm, IS = fs;
    for (int i = threadIdx.x; i < V_ / 4; i += 256) {
        float4 v = p4[i];
        v.x = expf(v.x - M) * IS;
        v.y = expf(v.y - M) * IS;
        v.z = expf(v.z - M) * IS;
        v.w = expf(v.w - M) * IS;
        p4[i] = v;
    }
}

// ---------------------------------------------------------------------------
// px / lnpx / nll accumulation. Grid (v-chunks, t). beta[t] staged in LDS.
// ---------------------------------------------------------------------------
__global__ __launch_bounds__(256) void px_kernel(
    const float* __restrict__ beta, const float* __restrict__ theta,
    const int* __restrict__ ts, const float* __restrict__ X,
    float* __restrict__ lnpx, float* __restrict__ nll_acc)
{
    __shared__ float sb[K_][256];
    int t = blockIdx.y;
    int tid = threadIdx.x;
    int v = blockIdx.x * 256 + tid;
    bool vok = v < V_;
    bool any = false;
    for (int b = 0; b < B_; ++b) any |= (ts[b] == t);
    if (!any) return;
    for (int k = 0; k < K_; ++k)
        sb[k][tid] = vok ? beta[((size_t)t * K_ + k) * V_ + v] : 0.f;
    __syncthreads();
    float acc = 0.f;
    for (int b = 0; b < B_; ++b) {
        if (ts[b] != t) continue;
        const float* th = theta + b * K_;
        float px = 0.f;
#pragma unroll
        for (int k = 0; k < K_; ++k) px += th[k] * sb[k][tid];
        float l = logf(px + 1e-6f);
        if (vok) {
            lnpx[(size_t)b * V_ + v] = l;
            acc += l * X[(size_t)b * V_ + v];
        }
    }
    for (int off = 32; off; off >>= 1) acc += __shfl_down(acc, off);
    __shared__ float red[4];
    int wid = tid >> 6, lane = tid & 63;
    if (lane == 0) red[wid] = acc;
    __syncthreads();
    if (tid == 0) atomicAdd(nll_acc, red[0] + red[1] + red[2] + red[3]);
}

// ---------------------------------------------------------------------------
// kl_alpha reduction over (K,T,E) in mu_q_alpha's native layout.
// ---------------------------------------------------------------------------
__global__ __launch_bounds__(256) void kl_alpha_kernel(
    const float* __restrict__ mu, const float* __restrict__ lsig,
    float* __restrict__ out)
{
    int idx = blockIdx.x * 256 + threadIdx.x;
    float term = 0.f;
    if (idx < K_ * T_ * E_) {
        int r = idx % (T_ * E_);
        int t = r / E_;
        float a = mu[idx];
        float q = lsig[idx];
        float pmu = (t > 0) ? mu[idx - E_] : 0.f;
        float pls = (t > 0) ? LOGD_ : 0.f;
        float d = a - pmu;
        term = 0.5f * ((expf(q) + d * d) / (expf(pls) + 1e-6f) - 1.f + pls - q);
    }
    for (int off = 32; off; off >>= 1) term += __shfl_down(term, off);
    __shared__ float red[4];
    int wid = threadIdx.x >> 6, lane = threadIdx.x & 63;
    if (lane == 0) red[wid] = term;
    __syncthreads();
    if (threadIdx.x == 0) atomicAdd(out, red[0] + red[1] + red[2] + red[3]);
}

__global__ void finalize_nll(const float* __restrict__ acc, float* __restrict__ out)
{
    *out = -acc[0] * (1.f / (float)B_);
}

// ---------------------------------------------------------------------------
extern "C" void kernel_launch(void* const* d_in, const int* in_sizes, int n_in,
                              void* d_out, int out_size, void* d_ws, size_t ws_size,
                              hipStream_t stream)
{
    const float* X          = (const float*)d_in[0];
    const int*   ts         = (const int*)d_in[1];
    const float* X_mean     = (const float*)d_in[2];
    const float* W_eta_map  = (const float*)d_in[3];
    const float* b_eta_map  = (const float*)d_in[4];
    const float* lstm_Wih   = (const float*)d_in[5];
    const float* lstm_Whh   = (const float*)d_in[6];
    const float* lstm_bih   = (const float*)d_in[7];
    const float* lstm_bhh   = (const float*)d_in[8];
    const float* W_qeta_mu  = (const float*)d_in[9];
    const float* b_qeta_mu  = (const float*)d_in[10];
    const float* W_qeta_ls  = (const float*)d_in[11];
    const float* b_qeta_ls  = (const float*)d_in[12];
    const float* W1         = (const float*)d_in[13];
    const float* b1         = (const float*)d_in[14];
    const float* W2         = (const float*)d_in[15];
    const float* b2         = (const float*)d_in[16];
    const float* W_qt_mu    = (const float*)d_in[17];
    const float* b_qt_mu    = (const float*)d_in[18];
    const float* W_qt_ls    = (const float*)d_in[19];
    const float* b_qt_ls    = (const float*)d_in[20];
    const float* mu_q_alpha = (const float*)d_in[21];
    const float* ls_q_alpha = (const float*)d_in[22];
    const float* emb        = (const float*)d_in[23];

    float* out     = (float*)d_out;
    float* o_theta = out;                          // [B,K]
    float* o_lnpx  = out + (size_t)B_ * K_;        // [B,V]
    float* o_beta  = o_lnpx + (size_t)B_ * V_;     // [T,K,V]
    float* o_scal  = o_beta + (size_t)T_ * K_ * V_; // nll, kl_alpha, kl_eta, kl_theta

    float* ws = (float*)d_ws;
    float* w_inv   = ws;               // 128
    float* w_rnn   = ws + 128;         // 12800
    float* w_seq0  = ws + 12928;       // 12800
    float* w_seq1  = ws + 25728;       // 12800
    float* w_xproj = ws + 38528;       // 51200
    float* w_etas  = ws + 89728;       // 2500
    float* w_h1    = ws + 92228;       // 102400
    float* w_h2    = ws + 194628;      // 102400
    float* w_mu    = ws + 297028;      // 6400
    float* w_ls    = ws + 303428;      // 6400
    float* w_nll   = ws + 309828;      // 1
    float* w_alph  = ws + 309832;      // 750000

    // zero accumulators (d_out / d_ws are poisoned before every launch)
    hipMemsetAsync(o_scal, 0, 4 * sizeof(float), stream);
    // one contiguous memset covers w_h1, w_h2, w_mu, w_ls, w_nll
    hipMemsetAsync(w_h1, 0, (size_t)(102400 + 102400 + 6400 + 6400 + 1) * sizeof(float), stream);
    hipMemsetAsync(w_rnn, 0, (size_t)T_ * HE_ * sizeof(float), stream);

    rowsum_inv<<<B_, 256, 0, stream>>>(X, w_inv);

    // rnn_in = X_mean @ W_eta_map^T + b_eta_map   [T,HE]
    // split-K: 125 chunks x 240 (= 30000), grid 4x1x125 = 500 blocks
    gemm_nt<<<dim3(HE_ / TN, 1, 125), 256, 0, stream>>>(
        X_mean, V_, T_, W_eta_map, V_, HE_, V_, w_rnn, HE_, nullptr, 3, 240);
    bias_act<<<(T_ * HE_ + 255) / 256, 256, 0, stream>>>(
        w_rnn, b_eta_map, T_ * HE_, HE_, 2);

    // 3-layer LSTM: per-layer input-projection GEMM + single-block scan
    const float* xin = w_rnn;
    float* louts[3] = { w_seq0, w_seq1, w_seq0 };
    for (int l = 0; l < L_; ++l) {
        hipMemsetAsync(w_xproj, 0, (size_t)T_ * 4 * HE_ * sizeof(float), stream);
        // K=256: 4 chunks x 64, grid 16x1x4 = 64 blocks
        gemm_nt<<<dim3(4 * HE_ / TN, 1, 4), 256, 0, stream>>>(
            xin, HE_, T_, lstm_Wih + (size_t)l * 4 * HE_ * HE_, HE_, 4 * HE_, HE_,
            w_xproj, 4 * HE_, nullptr, 3, 64);
        lstm_scan<<<1, 1024, 0, stream>>>(
            w_xproj, lstm_Whh + (size_t)l * 4 * HE_ * HE_,
            lstm_bih + l * 4 * HE_, lstm_bhh + l * 4 * HE_, louts[l]);
        xin = louts[l];
    }

    // eta recurrence + kl_eta (louts[2] == w_seq0 holds final rnn_out)
    eta_scan<<<1, 64, 0, stream>>>(w_seq0, W_qeta_mu, b_qeta_mu,
                                   W_qeta_ls, b_qeta_ls, w_etas, o_scal + 2);

    // C1 = X @ W1[:, :V]^T (unnormalized), split-K: 75 chunks x 400 (= 30000),
    // grid 13x2x75 = 1950 blocks; epilogue folds 1/rowsum + eta + bias + tanh
    gemm_nt<<<dim3((TH_ + TN - 1) / TN, (B_ + TM - 1) / TM, 75), 256, 0, stream>>>(
        X, V_, B_, W1, V_ + K_, TH_, V_, w_h1, TH_, nullptr, 3, 400);
    h1_epilogue<<<(B_ * TH_ + 255) / 256, 256, 0, stream>>>(
        w_h1, w_inv, w_etas, ts, W1, b1, w_h1);

    // h2 = tanh(h1 @ W2^T + b2), split-K: 10 chunks x 80 (= 800)
    gemm_nt<<<dim3((TH_ + TN - 1) / TN, (B_ + TM - 1) / TM, 10), 256, 0, stream>>>(
        w_h1, TH_, B_, W2, TH_, TH_, TH_, w_h2, TH_, nullptr, 3, 80);
    bias_act<<<(B_ * TH_ + 255) / 256, 256, 0, stream>>>(
        w_h2, b2, B_ * TH_, TH_, 1);

    // mu_t / ls_t: K=800, split-K: 25 chunks x 32
    gemm_nt<<<dim3(1, (B_ + TM - 1) / TM, 25), 256, 0, stream>>>(
        w_h2, TH_, B_, W_qt_mu, TH_, K_, TH_, w_mu, K_, nullptr, 3, 32);
    gemm_nt<<<dim3(1, (B_ + TM - 1) / TM, 25), 256, 0, stream>>>(
        w_h2, TH_, B_, W_qt_ls, TH_, K_, TH_, w_ls, K_, nullptr, 3, 32);
    bias_act<<<(B_ * K_ + 255) / 256, 256, 0, stream>>>(
        w_mu, b_qt_mu, B_ * K_, K_, 2);
    bias_act<<<(B_ * K_ + 255) / 256, 256, 0, stream>>>(
        w_ls, b_qt_ls, B_ * K_, K_, 2);

    theta_kernel<<<B_, 64, 0, stream>>>(w_mu, w_ls, w_etas, ts, o_theta, o_scal + 3);

    // beta: transpose alphas, logits GEMM into d_out, in-place softmax
    // (logits GEMM already has 18760 blocks -> no split needed)
    transpose_alphas<<<(T_ * K_ * E_ + 255) / 256, 256, 0, stream>>>(mu_q_alpha, w_alph);
    gemm_nt<<<dim3((V_ + TN - 1) / TN, (T_ * K_ + TM - 1) / TM, 1), 256, 0, stream>>>(
        w_alph, E_, T_ * K_, emb, E_, V_, E_, o_beta, V_, nullptr, 0, E_);
    softmax_rows<<<T_ * K_, 256, 0, stream>>>(o_beta);

    // px / lnpx / nll
    px_kernel<<<dim3((V_ + 255) / 256, T_), 256, 0, stream>>>(
        o_beta, o_theta, ts, X, o_lnpx, w_nll);

    kl_alpha_kernel<<<(K_ * T_ * E_ + 255) / 256, 256, 0, stream>>>(
        mu_q_alpha, ls_q_alpha, o_scal + 1);

    finalize_nll<<<1, 1, 0, stream>>>(w_nll, o_scal);
}

// Round 2
// 2755.696 us; speedup vs baseline: 4.4965x; 2.4173x over previous
//
#include <hip/hip_runtime.h>
#include <math.h>

// Problem constants
#define B_  128
#define V_  30000
#define T_  50
#define K_  50
#define HE_ 256
#define TH_ 800
#define E_  300
#define L_  3

#define LOGD_ (-5.2983173665480363f)   // log(0.005) in f32

// ---------------------------------------------------------------------------
// Generic f32 NT GEMM: C[M,N] = A[M,K] * B[N,K]^T  (A,B row-major, K contiguous)
// mode: 0 = plain store, 1 = tanh(x + bias[col]), 2 = x + bias[col]
//       3 = split-K atomic accumulate (C must be pre-zeroed; bias ignored)
// ---------------------------------------------------------------------------
#define TM 64
#define TN 64
#define TK 16

__global__ __launch_bounds__(256) void gemm_nt(
    const float* __restrict__ A, int lda, int M,
    const float* __restrict__ B, int ldb, int N,
    int K,
    float* __restrict__ C, int ldc,
    const float* __restrict__ bias, int mode, int kchunk)
{
    __shared__ float As[TK][TM + 4];
    __shared__ float Bs[TK][TN + 4];
    const int tid = threadIdx.x;
    const int bm = blockIdx.y * TM;
    const int bn = blockIdx.x * TN;
    const int tx = tid & 15;       // 0..15 col group
    const int ty = tid >> 4;       // 0..15 row group
    const int lr = tid >> 2;       // 0..63 tile row for loads
    const int lc = (tid & 3) << 2; // 0,4,8,12 k offset for loads

    float acc[4][4];
#pragma unroll
    for (int i = 0; i < 4; ++i)
#pragma unroll
        for (int j = 0; j < 4; ++j) acc[i][j] = 0.f;

    const int kbeg = blockIdx.z * kchunk;
    const int kend = min(K, kbeg + kchunk);

    for (int k0 = kbeg; k0 < kend; k0 += TK) {
        // stage A tile
        {
            float v0 = 0.f, v1 = 0.f, v2 = 0.f, v3 = 0.f;
            int gr = bm + lr;
            if (gr < M) {
                const float* p = A + (size_t)gr * lda + k0 + lc;
                int rem = K - (k0 + lc);
                if (rem >= 4) {
                    float2 a0 = *(const float2*)p;
                    float2 a1 = *(const float2*)(p + 2);
                    v0 = a0.x; v1 = a0.y; v2 = a1.x; v3 = a1.y;
                } else {
                    if (rem > 0) v0 = p[0];
                    if (rem > 1) v1 = p[1];
                    if (rem > 2) v2 = p[2];
                }
            }
            As[lc + 0][lr] = v0; As[lc + 1][lr] = v1;
            As[lc + 2][lr] = v2; As[lc + 3][lr] = v3;
        }
        // stage B tile
        {
            float v0 = 0.f, v1 = 0.f, v2 = 0.f, v3 = 0.f;
            int gr = bn + lr;
            if (gr < N) {
                const float* p = B + (size_t)gr * ldb + k0 + lc;
                int rem = K - (k0 + lc);
                if (rem >= 4) {
                    float2 a0 = *(const float2*)p;
                    float2 a1 = *(const float2*)(p + 2);
                    v0 = a0.x; v1 = a0.y; v2 = a1.x; v3 = a1.y;
                } else {
                    if (rem > 0) v0 = p[0];
                    if (rem > 1) v1 = p[1];
                    if (rem > 2) v2 = p[2];
                }
            }
            Bs[lc + 0][lr] = v0; Bs[lc + 1][lr] = v1;
            Bs[lc + 2][lr] = v2; Bs[lc + 3][lr] = v3;
        }
        __syncthreads();
#pragma unroll
        for (int kk = 0; kk < TK; ++kk) {
            float a[4], b[4];
#pragma unroll
            for (int i = 0; i < 4; ++i) a[i] = As[kk][ty * 4 + i];
#pragma unroll
            for (int j = 0; j < 4; ++j) b[j] = Bs[kk][tx * 4 + j];
#pragma unroll
            for (int i = 0; i < 4; ++i)
#pragma unroll
                for (int j = 0; j < 4; ++j) acc[i][j] += a[i] * b[j];
        }
        __syncthreads();
    }

#pragma unroll
    for (int i = 0; i < 4; ++i) {
        int row = bm + ty * 4 + i;
        if (row >= M) continue;
#pragma unroll
        for (int j = 0; j < 4; ++j) {
            int col = bn + tx * 4 + j;
            if (col >= N) continue;
            float v = acc[i][j];
            if (mode == 3) {
                atomicAdd(&C[(size_t)row * ldc + col], v);
            } else {
                if (mode == 1) v = tanhf(v + bias[col]);
                else if (mode == 2) v = v + bias[col];
                C[(size_t)row * ldc + col] = v;
            }
        }
    }
}

// ---------------------------------------------------------------------------
// Epilogue for split-K GEMMs: C[i] = (tanh)(C[i] + bias[col]).
// mode 1 = tanh(x+b), 2 = x+b
// ---------------------------------------------------------------------------
__global__ __launch_bounds__(256) void bias_act(
    float* __restrict__ C, const float* __restrict__ bias,
    int total, int N, int mode)
{
    int idx = blockIdx.x * 256 + threadIdx.x;
    if (idx >= total) return;
    int j = idx % N;
    float v = C[idx] + bias[j];
    if (mode == 1) v = tanhf(v);
    C[idx] = v;
}

// ---------------------------------------------------------------------------
// Row sums of X -> 1/sum
// ---------------------------------------------------------------------------
__global__ __launch_bounds__(256) void rowsum_inv(const float* __restrict__ X,
                                                  float* __restrict__ inv)
{
    int b = blockIdx.x;
    const float4* p = (const float4*)(X + (size_t)b * V_);
    float s = 0.f;
    for (int i = threadIdx.x; i < V_ / 4; i += 256) {
        float4 v = p[i];
        s += v.x + v.y + v.z + v.w;
    }
    for (int off = 32; off; off >>= 1) s += __shfl_down(s, off);
    __shared__ float red[4];
    int wid = threadIdx.x >> 6, lane = threadIdx.x & 63;
    if (lane == 0) red[wid] = s;
    __syncthreads();
    if (threadIdx.x == 0) inv[b] = 1.f / (red[0] + red[1] + red[2] + red[3]);
}

// ---------------------------------------------------------------------------
// Fused 3-layer LSTM, 32 blocks cooperating via device-scope atomic barrier.
// Block b owns h indices [b*8, b*8+8) -> 32 gate rows (i/f/g/o x 8).
// 8 threads per gate row, each holding 32 floats of Wih + 32 of Whh in VGPRs.
// x_t and h_{t-1} staged in bank-padded LDS each step; h exchanged through a
// ping-ponged global buffer; one grid barrier per timestep.
// Input projection (Wih @ x) is fused, so no Xproj GEMMs are needed.
// ---------------------------------------------------------------------------
#define NLB 32

__global__ __launch_bounds__(256) void lstm_all(
    const float* __restrict__ rnn_in,   // [T,HE] layer-0 input
    const float* __restrict__ Wih,      // [L,4HE,HE]
    const float* __restrict__ Whh,      // [L,4HE,HE]
    const float* __restrict__ bih,      // [L,4HE]
    const float* __restrict__ bhh,      // [L,4HE]
    float* __restrict__ houtA,          // [T,HE] layer-0 out
    float* __restrict__ houtB,          // [T,HE] layer-1 out
    float* __restrict__ houtF,          // [T,HE] layer-2 out (final)
    float* __restrict__ hping,          // [2,HE]
    int* __restrict__ barcnt)           // zeroed before launch
{
    __shared__ float sx[8 * 36];  // 8 segments of 32 floats, stride 36 (bank pad)
    __shared__ float sh[8 * 36];
    __shared__ float sg[32];
    const int tid = threadIdx.x;
    const int blk = blockIdx.x;
    const int row_local = tid >> 3;        // 0..31
    const int chunk = tid & 7;             // 0..7
    const int gate = row_local >> 3;       // 0..3 (i,f,g,o)
    const int jloc = row_local & 7;        // 0..7
    const int gr = gate * HE_ + blk * 8 + jloc;  // global gate row 0..1023
    const int seg = tid >> 5, sidx = tid & 31;

    for (int l = 0; l < L_; ++l) {
        // ---- preload this thread's weight slices into registers ----
        float4 wih[8], whh[8];
        const float4* pi = (const float4*)(Wih + ((size_t)l * 4 * HE_ + gr) * HE_ + chunk * 32);
        const float4* pw = (const float4*)(Whh + ((size_t)l * 4 * HE_ + gr) * HE_ + chunk * 32);
#pragma unroll
        for (int q = 0; q < 8; ++q) { wih[q] = pi[q]; whh[q] = pw[q]; }
        const float bias = bih[l * 4 * HE_ + gr] + bhh[l * 4 * HE_ + gr];
        const float* xs = (l == 0) ? rnn_in : ((l == 1) ? houtA : houtB);
        float* hd = (l == 0) ? houtA : ((l == 1) ? houtB : houtF);
        float cst = 0.f;

        for (int t = 0; t < T_; ++t) {
            const int wb = t & 1, rb = wb ^ 1;
            float xv = xs[t * HE_ + tid];
            float hv = (t > 0) ? hping[rb * HE_ + tid] : 0.f;
            sx[seg * 36 + sidx] = xv;
            sh[seg * 36 + sidx] = hv;
            __syncthreads();

            float acc = 0.f;
#pragma unroll
            for (int q = 0; q < 8; ++q) {
                float4 a = *(const float4*)&sx[chunk * 36 + q * 4];
                float4 b = *(const float4*)&sh[chunk * 36 + q * 4];
                float4 wa = wih[q], wc = whh[q];
                acc += wa.x * a.x + wa.y * a.y + wa.z * a.z + wa.w * a.w
                     + wc.x * b.x + wc.y * b.y + wc.z * b.z + wc.w * b.w;
            }
            // reduce the 8 chunk-partials (consecutive lanes, in-wave)
            acc += __shfl_xor(acc, 1);
            acc += __shfl_xor(acc, 2);
            acc += __shfl_xor(acc, 4);
            if (chunk == 0) sg[row_local] = acc + bias;
            __syncthreads();

            if (tid < 8) {
                float gi = sg[tid], gf = sg[8 + tid], gg = sg[16 + tid], go = sg[24 + tid];
                float si = 1.f / (1.f + expf(-gi));
                float sf = 1.f / (1.f + expf(-gf));
                float so = 1.f / (1.f + expf(-go));
                cst = sf * cst + si * tanhf(gg);
                float hn = so * tanhf(cst);
                int j = blk * 8 + tid;
                hping[wb * HE_ + j] = hn;
                hd[t * HE_ + j] = hn;
            }

            // ---- grid barrier (release by writing wave, arrive, spin, acquire) ----
            if (tid < 64) __threadfence();
            __syncthreads();
            if (tid == 0) {
                atomicAdd(barcnt, 1);
                const int tgt = (l * T_ + t + 1) * NLB;
                while (atomicAdd(barcnt, 0) < tgt) __builtin_amdgcn_s_sleep(2);
                __threadfence();
            }
            __syncthreads();
        }
    }
}

// ---------------------------------------------------------------------------
// Sequential eta recurrence (tiny). One wave. Also emits kl_eta.
// ---------------------------------------------------------------------------
__global__ __launch_bounds__(64) void eta_scan(
    const float* __restrict__ rnn_out,  // [T,HE]
    const float* __restrict__ Wmu, const float* __restrict__ bmu,
    const float* __restrict__ Wls, const float* __restrict__ bls,
    float* __restrict__ etas,           // [T,K]
    float* __restrict__ kl_eta_out)
{
    __shared__ float hbuf[HE_ + K_];
    const int lane = threadIdx.x;
    if (lane < K_) hbuf[HE_ + lane] = 0.f;
    float kl = 0.f;
    __syncthreads();
    for (int t = 0; t < T_; ++t) {
        for (int i = lane; i < HE_; i += 64) hbuf[i] = rnn_out[t * HE_ + i];
        __syncthreads();
        float mu = 0.f;
        if (lane < K_) {
            const float* wm = Wmu + lane * (HE_ + K_);
            const float* wl = Wls + lane * (HE_ + K_);
            float am = 0.f, al = 0.f;
            for (int i = 0; i < HE_ + K_; ++i) {
                float hv = hbuf[i];
                am += wm[i] * hv;
                al += wl[i] * hv;
            }
            mu = am + bmu[lane];
            float ls = al + bls[lane];
            float eprev = hbuf[HE_ + lane];
            float pls = (t == 0) ? 0.f : LOGD_;
            float d = mu - eprev;
            kl += 0.5f * ((expf(ls) + d * d) / (expf(pls) + 1e-6f) - 1.f + pls - ls);
            etas[t * K_ + lane] = mu;
        }
        __syncthreads();
        if (lane < K_) hbuf[HE_ + lane] = mu;
        __syncthreads();
    }
    for (int off = 32; off; off >>= 1) kl += __shfl_down(kl, off);
    if (lane == 0) *kl_eta_out = kl;
}

// ---------------------------------------------------------------------------
// h1 = tanh(inv[b]*C1 + etas[ts[b]]·W1[:,V:] + b1)   (in place on C1)
// ---------------------------------------------------------------------------
__global__ __launch_bounds__(256) void h1_epilogue(
    const float* __restrict__ C1, const float* __restrict__ inv,
    const float* __restrict__ etas, const int* __restrict__ ts,
    const float* __restrict__ W1, const float* __restrict__ b1,
    float* __restrict__ h1)
{
    int idx = blockIdx.x * 256 + threadIdx.x;
    if (idx >= B_ * TH_) return;
    int b = idx / TH_, j = idx % TH_;
    const float* e = etas + ts[b] * K_;
    const float* w = W1 + (size_t)j * (V_ + K_) + V_;
    float s = 0.f;
#pragma unroll
    for (int k = 0; k < K_; ++k) s += e[k] * w[k];
    h1[idx] = tanhf(C1[idx] * inv[b] + s + b1[j]);
}

// ---------------------------------------------------------------------------
// theta = softmax(mu_t) rows; kl_theta accumulated. One block (1 wave) per b.
// ---------------------------------------------------------------------------
__global__ __launch_bounds__(64) void theta_kernel(
    const float* __restrict__ mu_t, const float* __restrict__ ls_t,
    const float* __restrict__ etas, const int* __restrict__ ts,
    float* __restrict__ theta, float* __restrict__ kl_out)
{
    int b = blockIdx.x;
    int lane = threadIdx.x;
    bool ok = lane < K_;
    float m = ok ? mu_t[b * K_ + lane] : -3.4e38f;
    float mx = m;
    for (int off = 32; off; off >>= 1) mx = fmaxf(mx, __shfl_down(mx, off));
    mx = __shfl(mx, 0);
    float e = ok ? expf(m - mx) : 0.f;
    float s = e;
    for (int off = 32; off; off >>= 1) s += __shfl_down(s, off);
    s = __shfl(s, 0);
    if (ok) theta[b * K_ + lane] = e / s;
    float kl = 0.f;
    if (ok) {
        float ls = ls_t[b * K_ + lane];
        float d = m - etas[ts[b] * K_ + lane];
        kl = 0.5f * ((expf(ls) + d * d) / (1.f + 1e-6f) - 1.f - ls);
    }
    for (int off = 32; off; off >>= 1) kl += __shfl_down(kl, off);
    if (lane == 0) atomicAdd(kl_out, kl);
}

// ---------------------------------------------------------------------------
// alphas[t*K+k, e] = mu_q_alpha[k, t, e]
// ---------------------------------------------------------------------------
__global__ __launch_bounds__(256) void transpose_alphas(
    const float* __restrict__ mu, float* __restrict__ out)
{
    int idx = blockIdx.x * 256 + threadIdx.x;
    if (idx >= T_ * K_ * E_) return;
    int t = idx / (K_ * E_);
    int r = idx % (K_ * E_);
    int k = r / E_;
    int e = r % E_;
    out[idx] = mu[((size_t)k * T_ + t) * E_ + e];
}

// ---------------------------------------------------------------------------
// In-place row softmax (rows of length V), online max/sum pass + write pass.
// ---------------------------------------------------------------------------
__global__ __launch_bounds__(256) void softmax_rows(float* __restrict__ logits)
{
    int row = blockIdx.x;
    float4* p4 = (float4*)(logits + (size_t)row * V_);
    float m = -3.4e38f, s = 0.f;
    for (int i = threadIdx.x; i < V_ / 4; i += 256) {
        float4 v = p4[i];
        float vm = fmaxf(fmaxf(v.x, v.y), fmaxf(v.z, v.w));
        if (vm > m) { s *= expf(m - vm); m = vm; }
        s += expf(v.x - m) + expf(v.y - m) + expf(v.z - m) + expf(v.w - m);
    }
    // wave combine (m,s)
    for (int off = 32; off; off >>= 1) {
        float om = __shfl_down(m, off);
        float os = __shfl_down(s, off);
        float nm = fmaxf(m, om);
        s = s * expf(m - nm) + os * expf(om - nm);
        m = nm;
    }
    __shared__ float redm[4], reds[4];
    __shared__ float fm, fs;
    int wid = threadIdx.x >> 6, lane = threadIdx.x & 63;
    if (lane == 0) { redm[wid] = m; reds[wid] = s; }
    __syncthreads();
    if (threadIdx.x == 0) {
        float M = fmaxf(fmaxf(redm[0], redm[1]), fmaxf(redm[2], redm[3]));
        float S = reds[0] * expf(redm[0] - M) + reds[1] * expf(redm[1] - M) +
                  reds[2] * expf(redm[2] - M) + reds[3] * expf(redm[3] - M);
        fm = M; fs = 1.f / S;
    }
    __syncthreads();
    float M = fm, IS = fs;
    for (int i = threadIdx.x; i < V_ / 4; i += 256) {
        float4 v = p4[i];
        v.x = expf(v.x - M) * IS;
        v.y = expf(v.y - M) * IS;
        v.z = expf(v.z - M) * IS;
        v.w = expf(v.w - M) * IS;
        p4[i] = v;
    }
}

// ---------------------------------------------------------------------------
// px / lnpx / nll accumulation. Grid (v-chunks, t). beta[t] staged in LDS.
// ---------------------------------------------------------------------------
__global__ __launch_bounds__(256) void px_kernel(
    const float* __restrict__ beta, const float* __restrict__ theta,
    const int* __restrict__ ts, const float* __restrict__ X,
    float* __restrict__ lnpx, float* __restrict__ nll_acc)
{
    __shared__ float sb[K_][256];
    int t = blockIdx.y;
    int tid = threadIdx.x;
    int v = blockIdx.x * 256 + tid;
    bool vok = v < V_;
    bool any = false;
    for (int b = 0; b < B_; ++b) any |= (ts[b] == t);
    if (!any) return;
    for (int k = 0; k < K_; ++k)
        sb[k][tid] = vok ? beta[((size_t)t * K_ + k) * V_ + v] : 0.f;
    __syncthreads();
    float acc = 0.f;
    for (int b = 0; b < B_; ++b) {
        if (ts[b] != t) continue;
        const float* th = theta + b * K_;
        float px = 0.f;
#pragma unroll
        for (int k = 0; k < K_; ++k) px += th[k] * sb[k][tid];
        float l = logf(px + 1e-6f);
        if (vok) {
            lnpx[(size_t)b * V_ + v] = l;
            acc += l * X[(size_t)b * V_ + v];
        }
    }
    for (int off = 32; off; off >>= 1) acc += __shfl_down(acc, off);
    __shared__ float red[4];
    int wid = tid >> 6, lane = tid & 63;
    if (lane == 0) red[wid] = acc;
    __syncthreads();
    if (tid == 0) atomicAdd(nll_acc, red[0] + red[1] + red[2] + red[3]);
}

// ---------------------------------------------------------------------------
// kl_alpha reduction over (K,T,E) in mu_q_alpha's native layout.
// ---------------------------------------------------------------------------
__global__ __launch_bounds__(256) void kl_alpha_kernel(
    const float* __restrict__ mu, const float* __restrict__ lsig,
    float* __restrict__ out)
{
    int idx = blockIdx.x * 256 + threadIdx.x;
    float term = 0.f;
    if (idx < K_ * T_ * E_) {
        int r = idx % (T_ * E_);
        int t = r / E_;
        float a = mu[idx];
        float q = lsig[idx];
        float pmu = (t > 0) ? mu[idx - E_] : 0.f;
        float pls = (t > 0) ? LOGD_ : 0.f;
        float d = a - pmu;
        term = 0.5f * ((expf(q) + d * d) / (expf(pls) + 1e-6f) - 1.f + pls - q);
    }
    for (int off = 32; off; off >>= 1) term += __shfl_down(term, off);
    __shared__ float red[4];
    int wid = threadIdx.x >> 6, lane = threadIdx.x & 63;
    if (lane == 0) red[wid] = term;
    __syncthreads();
    if (threadIdx.x == 0) atomicAdd(out, red[0] + red[1] + red[2] + red[3]);
}

__global__ void finalize_nll(const float* __restrict__ acc, float* __restrict__ out)
{
    *out = -acc[0] * (1.f / (float)B_);
}

// ---------------------------------------------------------------------------
extern "C" void kernel_launch(void* const* d_in, const int* in_sizes, int n_in,
                              void* d_out, int out_size, void* d_ws, size_t ws_size,
                              hipStream_t stream)
{
    const float* X          = (const float*)d_in[0];
    const int*   ts         = (const int*)d_in[1];
    const float* X_mean     = (const float*)d_in[2];
    const float* W_eta_map  = (const float*)d_in[3];
    const float* b_eta_map  = (const float*)d_in[4];
    const float* lstm_Wih   = (const float*)d_in[5];
    const float* lstm_Whh   = (const float*)d_in[6];
    const float* lstm_bih   = (const float*)d_in[7];
    const float* lstm_bhh   = (const float*)d_in[8];
    const float* W_qeta_mu  = (const float*)d_in[9];
    const float* b_qeta_mu  = (const float*)d_in[10];
    const float* W_qeta_ls  = (const float*)d_in[11];
    const float* b_qeta_ls  = (const float*)d_in[12];
    const float* W1         = (const float*)d_in[13];
    const float* b1         = (const float*)d_in[14];
    const float* W2         = (const float*)d_in[15];
    const float* b2         = (const float*)d_in[16];
    const float* W_qt_mu    = (const float*)d_in[17];
    const float* b_qt_mu    = (const float*)d_in[18];
    const float* W_qt_ls    = (const float*)d_in[19];
    const float* b_qt_ls    = (const float*)d_in[20];
    const float* mu_q_alpha = (const float*)d_in[21];
    const float* ls_q_alpha = (const float*)d_in[22];
    const float* emb        = (const float*)d_in[23];

    float* out     = (float*)d_out;
    float* o_theta = out;                          // [B,K]
    float* o_lnpx  = out + (size_t)B_ * K_;        // [B,V]
    float* o_beta  = o_lnpx + (size_t)B_ * V_;     // [T,K,V]
    float* o_scal  = o_beta + (size_t)T_ * K_ * V_; // nll, kl_alpha, kl_eta, kl_theta

    float* ws = (float*)d_ws;
    float* w_inv   = ws;               // 128
    float* w_rnn   = ws + 128;         // 12800
    float* w_seq0  = ws + 12928;       // 12800  (final LSTM layer out)
    float* w_seq1  = ws + 25728;       // 12800  (unused now)
    float* w_houtA = ws + 38528;       // 12800  (layer-0 out)
    float* w_houtB = ws + 51328;       // 12800  (layer-1 out)
    float* w_hping = ws + 64128;       // 512
    float* w_barc  = ws + 64640;       // 1 (int)
    float* w_etas  = ws + 89728;       // 2500
    float* w_h1    = ws + 92228;       // 102400
    float* w_h2    = ws + 194628;      // 102400
    float* w_mu    = ws + 297028;      // 6400
    float* w_ls    = ws + 303428;      // 6400
    float* w_nll   = ws + 309828;      // 1
    float* w_alph  = ws + 309832;      // 750000
    (void)w_seq1;

    // zero accumulators (d_out / d_ws are poisoned before every launch)
    hipMemsetAsync(o_scal, 0, 4 * sizeof(float), stream);
    // one contiguous memset covers w_h1, w_h2, w_mu, w_ls, w_nll
    hipMemsetAsync(w_h1, 0, (size_t)(102400 + 102400 + 6400 + 6400 + 1) * sizeof(float), stream);
    hipMemsetAsync(w_rnn, 0, (size_t)T_ * HE_ * sizeof(float), stream);
    hipMemsetAsync(w_barc, 0, sizeof(int), stream);

    rowsum_inv<<<B_, 256, 0, stream>>>(X, w_inv);

    // rnn_in = X_mean @ W_eta_map^T + b_eta_map   [T,HE]
    // split-K: 125 chunks x 240 (= 30000), grid 4x1x125 = 500 blocks
    gemm_nt<<<dim3(HE_ / TN, 1, 125), 256, 0, stream>>>(
        X_mean, V_, T_, W_eta_map, V_, HE_, V_, w_rnn, HE_, nullptr, 3, 240);
    bias_act<<<(T_ * HE_ + 255) / 256, 256, 0, stream>>>(
        w_rnn, b_eta_map, T_ * HE_, HE_, 2);

    // fused 3-layer LSTM (input projection fused; grid-barrier per step)
    lstm_all<<<NLB, 256, 0, stream>>>(
        w_rnn, lstm_Wih, lstm_Whh, lstm_bih, lstm_bhh,
        w_houtA, w_houtB, w_seq0, w_hping, (int*)w_barc);

    // eta recurrence + kl_eta (w_seq0 holds final rnn_out)
    eta_scan<<<1, 64, 0, stream>>>(w_seq0, W_qeta_mu, b_qeta_mu,
                                   W_qeta_ls, b_qeta_ls, w_etas, o_scal + 2);

    // C1 = X @ W1[:, :V]^T (unnormalized), split-K: 75 chunks x 400 (= 30000),
    // grid 13x2x75 = 1950 blocks; epilogue folds 1/rowsum + eta + bias + tanh
    gemm_nt<<<dim3((TH_ + TN - 1) / TN, (B_ + TM - 1) / TM, 75), 256, 0, stream>>>(
        X, V_, B_, W1, V_ + K_, TH_, V_, w_h1, TH_, nullptr, 3, 400);
    h1_epilogue<<<(B_ * TH_ + 255) / 256, 256, 0, stream>>>(
        w_h1, w_inv, w_etas, ts, W1, b1, w_h1);

    // h2 = tanh(h1 @ W2^T + b2), split-K: 10 chunks x 80 (= 800)
    gemm_nt<<<dim3((TH_ + TN - 1) / TN, (B_ + TM - 1) / TM, 10), 256, 0, stream>>>(
        w_h1, TH_, B_, W2, TH_, TH_, TH_, w_h2, TH_, nullptr, 3, 80);
    bias_act<<<(B_ * TH_ + 255) / 256, 256, 0, stream>>>(
        w_h2, b2, B_ * TH_, TH_, 1);

    // mu_t / ls_t: K=800, split-K: 25 chunks x 32
    gemm_nt<<<dim3(1, (B_ + TM - 1) / TM, 25), 256, 0, stream>>>(
        w_h2, TH_, B_, W_qt_mu, TH_, K_, TH_, w_mu, K_, nullptr, 3, 32);
    gemm_nt<<<dim3(1, (B_ + TM - 1) / TM, 25), 256, 0, stream>>>(
        w_h2, TH_, B_, W_qt_ls, TH_, K_, TH_, w_ls, K_, nullptr, 3, 32);
    bias_act<<<(B_ * K_ + 255) / 256, 256, 0, stream>>>(
        w_mu, b_qt_mu, B_ * K_, K_, 2);
    bias_act<<<(B_ * K_ + 255) / 256, 256, 0, stream>>>(
        w_ls, b_qt_ls, B_ * K_, K_, 2);

    theta_kernel<<<B_, 64, 0, stream>>>(w_mu, w_ls, w_etas, ts, o_theta, o_scal + 3);

    // beta: transpose alphas, logits GEMM into d_out, in-place softmax
    transpose_alphas<<<(T_ * K_ * E_ + 255) / 256, 256, 0, stream>>>(mu_q_alpha, w_alph);
    gemm_nt<<<dim3((V_ + TN - 1) / TN, (T_ * K_ + TM - 1) / TM, 1), 256, 0, stream>>>(
        w_alph, E_, T_ * K_, emb, E_, V_, E_, o_beta, V_, nullptr, 0, E_);
    softmax_rows<<<T_ * K_, 256, 0, stream>>>(o_beta);

    // px / lnpx / nll
    px_kernel<<<dim3((V_ + 255) / 256, T_), 256, 0, stream>>>(
        o_beta, o_theta, ts, X, o_lnpx, w_nll);

    kl_alpha_kernel<<<(K_ * T_ * E_ + 255) / 256, 256, 0, stream>>>(
        mu_q_alpha, ls_q_alpha, o_scal + 1);

    finalize_nll<<<1, 1, 0, stream>>>(w_nll, o_scal);
}